// Round 1
// baseline (590.776 us; speedup 1.0000x reference)
//
#include <hip/hip_runtime.h>
#include <stdint.h>

#define N_TOK 8192
#define HDIM  1024
#define NEXP  8
#define CAP   16384   // per-expert rowid list capacity (count[e] <= 8192 provably)

typedef __bf16 bf16x8 __attribute__((ext_vector_type(8)));
typedef float  f32x4  __attribute__((ext_vector_type(4)));

__device__ inline unsigned short f2bf(float f) {
  union { float f; unsigned u; } v; v.f = f;
  return (unsigned short)((v.u + 0x7fffu + ((v.u >> 16) & 1u)) >> 16);  // RNE
}

__device__ inline void gld_lds16(const void* gptr, void* lptr) {
  __builtin_amdgcn_global_load_lds(
      (const __attribute__((address_space(1))) void*)(uintptr_t)gptr,
      (__attribute__((address_space(3))) void*)(uintptr_t)lptr,
      16, 0, 0);
}

// ---------------- f32 -> bf16 conversion (weights) ----------------
__global__ __launch_bounds__(256) void cvt_kernel(const float* __restrict__ src,
                                                  unsigned short* __restrict__ dst,
                                                  int n4) {
  int i = blockIdx.x * 256 + threadIdx.x;
  int stride = gridDim.x * 256;
  for (; i < n4; i += stride) {
    float4 v = reinterpret_cast<const float4*>(src)[i];
    ushort4 o;
    o.x = f2bf(v.x); o.y = f2bf(v.y); o.z = f2bf(v.z); o.w = f2bf(v.w);
    reinterpret_cast<ushort4*>(dst)[i] = o;
  }
}

// ---------------- router: logits, top-2, softmax, dispatch lists ----------------
__global__ __launch_bounds__(256) void router_kernel(
    const float* __restrict__ tokens, const float* __restrict__ rw,
    unsigned short* __restrict__ tokb, int* __restrict__ counts,
    int* __restrict__ rowids, float* __restrict__ probs) {
  int wid = threadIdx.x >> 6, lane = threadIdx.x & 63;
  int n = blockIdx.x * 4 + wid;
  const float* trow = tokens + (size_t)n * HDIM;
  float acc[NEXP];
#pragma unroll
  for (int e = 0; e < NEXP; e++) acc[e] = 0.f;
  for (int c = lane; c < HDIM; c += 64) {
    float tv = trow[c];
    tokb[(size_t)n * HDIM + c] = f2bf(tv);
#pragma unroll
    for (int e = 0; e < NEXP; e++) acc[e] += tv * rw[e * HDIM + c];
  }
#pragma unroll
  for (int e = 0; e < NEXP; e++) {
#pragma unroll
    for (int off = 32; off > 0; off >>= 1) acc[e] += __shfl_xor(acc[e], off, 64);
  }
  if (lane == 0) {
    int e0 = 0; float s0 = acc[0];
#pragma unroll
    for (int e = 1; e < NEXP; e++) if (acc[e] > s0) { s0 = acc[e]; e0 = e; }
    int e1 = -1; float s1 = -3.4e38f;
#pragma unroll
    for (int e = 0; e < NEXP; e++) if (e != e0 && acc[e] > s1) { s1 = acc[e]; e1 = e; }
    float z  = expf(s1 - s0);
    float p0 = 1.f / (1.f + z);
    float p1 = z * p0;
    int pos0 = atomicAdd(&counts[e0], 1);
    rowids[e0 * CAP + pos0] = 2 * n;
    probs[2 * n] = p0;
    int pos1 = atomicAdd(&counts[e1], 1);
    rowids[e1 * CAP + pos1] = 2 * n + 1;
    probs[2 * n + 1] = p1;
  }
}

// ---------------- gathered NT bf16 GEMM: MODE 0 = fc1(+gelu->H), MODE 1 = fc2(+prob->out) ---------
// C[r][c] = sum_k A[row(r)][k] * W[c][k]   (both operands K-contiguous)
template <int MODE>
__global__ __launch_bounds__(256) void moe_gemm(
    const unsigned short* __restrict__ Abase,  // tokb (MODE0) / Hbuf (MODE1)
    const unsigned short* __restrict__ Wb,     // w1b  (MODE0) / w2b  (MODE1)
    const float* __restrict__ bias,            // b1 / b2
    const int* __restrict__ counts, const int* __restrict__ rowids,
    const float* __restrict__ probs,
    unsigned short* __restrict__ Hbuf, float* __restrict__ out) {
  constexpr int CB   = MODE ? 8 : 16;      // 128-col blocks over N
  constexpr int KT   = MODE ? 32 : 16;     // K / 64
  constexpr int NCOL = MODE ? 1024 : 2048; // N per expert
  constexpr int KDIM = MODE ? 2048 : 1024;

  int bid = blockIdx.x;
  int cb = bid % CB;
  int rb = (bid / CB) & 63;
  int e  = bid / (CB * 64);
  int ce = counts[e];
  if (rb * 128 >= ce) return;
  const int* rl = rowids + e * CAP + rb * 128;

  int t = threadIdx.x;
  __shared__ __align__(16) char smem[32768];  // A tile [128][64]bf16 @0, B tile @16384

  // staging: chunk c = i*256+t covers 16B at LDS byte c*16; row=c>>3, phys col-chunk=c&7
  // source col-chunk = (c&7) ^ (row&7)  (XOR swizzle, involution), == (t&7)^((t>>3)&7)
  int jsrc = (t & 7) ^ ((t >> 3) & 7);
  const char* asrc[4];
  const char* bsrc[4];
#pragma unroll
  for (int i = 0; i < 4; i++) {
    int r = i * 32 + (t >> 3);
    int rid = (rb * 128 + r < ce) ? rl[r] : rl[0];  // clamp tail to a valid row
    long arow = MODE ? (long)rid : (long)(rid >> 1);
    asrc[i] = (const char*)(Abase + arow * KDIM) + jsrc * 16;
    bsrc[i] = (const char*)(Wb + ((long)e * NCOL + cb * 128 + r) * KDIM) + jsrc * 16;
  }
  char* adst = smem + t * 16;
  char* bdst = smem + 16384 + t * 16;

  f32x4 acc[4][4];
#pragma unroll
  for (int mi = 0; mi < 4; mi++)
#pragma unroll
    for (int ni = 0; ni < 4; ni++) {
      f32x4 z = {0.f, 0.f, 0.f, 0.f};
      acc[mi][ni] = z;
    }

  int lane = t & 63, wid = t >> 6;
  int wr = wid >> 1, wc = wid & 1;        // 2x2 wave grid, 64x64 per wave
  int lr = lane >> 4, lc = lane & 15;

  for (int kt = 0; kt < KT; kt++) {
#pragma unroll
    for (int i = 0; i < 4; i++) {
      gld_lds16(asrc[i] + kt * 128, adst + i * 4096);
      gld_lds16(bsrc[i] + kt * 128, bdst + i * 4096);
    }
    __syncthreads();
#pragma unroll
    for (int ks = 0; ks < 2; ks++) {
      bf16x8 af[4], bfr[4];
#pragma unroll
      for (int mi = 0; mi < 4; mi++) {
        int r = wr * 64 + mi * 16 + lc;
        int j = ks * 4 + lr;
        af[mi] = *(const bf16x8*)(smem + r * 128 + ((j ^ (r & 7)) * 16));
      }
#pragma unroll
      for (int ni = 0; ni < 4; ni++) {
        int r = wc * 64 + ni * 16 + lc;
        int j = ks * 4 + lr;
        bfr[ni] = *(const bf16x8*)(smem + 16384 + r * 128 + ((j ^ (r & 7)) * 16));
      }
#pragma unroll
      for (int mi = 0; mi < 4; mi++)
#pragma unroll
        for (int ni = 0; ni < 4; ni++)
          acc[mi][ni] = __builtin_amdgcn_mfma_f32_16x16x32_bf16(af[mi], bfr[ni], acc[mi][ni], 0, 0, 0);
    }
    __syncthreads();
  }

  // epilogue: C/D layout col=lane&15, row=(lane>>4)*4+reg (m89-verified)
#pragma unroll
  for (int mi = 0; mi < 4; mi++) {
#pragma unroll
    for (int r4 = 0; r4 < 4; r4++) {
      int lrow = wr * 64 + mi * 16 + lr * 4 + r4;
      if (rb * 128 + lrow < ce) {
        int rid = rl[lrow];
#pragma unroll
        for (int ni = 0; ni < 4; ni++) {
          int col = cb * 128 + wc * 64 + ni * 16 + lc;
          float x = acc[mi][ni][r4] + bias[e * NCOL + col];
          if constexpr (MODE == 0) {
            x = 0.5f * x * (1.f + erff(x * 0.70710678118654752f));  // exact gelu
            Hbuf[(long)rid * 2048 + col] = f2bf(x);
          } else {
            atomicAdd(out + (long)(rid >> 1) * HDIM + col, x * probs[rid]);
          }
        }
      }
    }
  }
}

extern "C" void kernel_launch(void* const* d_in, const int* in_sizes, int n_in,
                              void* d_out, int out_size, void* d_ws, size_t ws_size,
                              hipStream_t stream) {
  const float* tokens   = (const float*)d_in[0];
  const float* router_w = (const float*)d_in[1];
  const float* w1       = (const float*)d_in[2];
  const float* b1       = (const float*)d_in[3];
  const float* w2       = (const float*)d_in[4];
  const float* b2       = (const float*)d_in[5];
  float* out = (float*)d_out;

  // ws layout (bytes):
  //   0        counts[8]
  //   64       rowids[8][16384] int          (512 KiB)
  //   524352   probs[16384] f32              (64 KiB)
  //   1 MiB    tokens_bf16 [8192][1024]      (16 MiB)
  //   +16M     w1b [8][2048][1024] bf16      (32 MiB)
  //   +48M     w2b [8][1024][2048] bf16      (32 MiB)
  //   +80M     Hbuf [16384][2048] bf16       (64 MiB)   total ~145 MiB
  char* ws = (char*)d_ws;
  int*            counts = (int*)ws;
  int*            rowids = (int*)(ws + 64);
  float*          probs  = (float*)(ws + 64 + NEXP * CAP * 4);
  unsigned short* tokb   = (unsigned short*)(ws + (1u << 20));
  unsigned short* w1b    = (unsigned short*)(ws + (1u << 20) + 16777216u);
  unsigned short* w2b    = (unsigned short*)(ws + (1u << 20) + 16777216u + 33554432u);
  unsigned short* Hbuf   = (unsigned short*)(ws + (1u << 20) + 16777216u + 67108864u);

  hipMemsetAsync(counts, 0, 64, stream);
  hipMemsetAsync(d_out, 0, (size_t)out_size * sizeof(float), stream);

  cvt_kernel<<<2048, 256, 0, stream>>>(w1, w1b, NEXP * 2048 * 1024 / 4);
  cvt_kernel<<<2048, 256, 0, stream>>>(w2, w2b, NEXP * 1024 * 2048 / 4);
  router_kernel<<<N_TOK / 4, 256, 0, stream>>>(tokens, router_w, tokb, counts, rowids, probs);
  moe_gemm<0><<<NEXP * 64 * 16, 256, 0, stream>>>(tokb, w1b, b1, counts, rowids, probs, Hbuf, out);
  moe_gemm<1><<<NEXP * 64 * 8, 256, 0, stream>>>(Hbuf, w2b, b2, counts, rowids, probs, Hbuf, out);
}

// Round 2
// 425.323 us; speedup vs baseline: 1.3890x; 1.3890x over previous
//
#include <hip/hip_runtime.h>
#include <stdint.h>

#define N_TOK 8192
#define HDIM  1024
#define NEXP  8
#define CAP   16384   // per-expert rowid list capacity

typedef __bf16 bf16x8 __attribute__((ext_vector_type(8)));
typedef float  f32x4  __attribute__((ext_vector_type(4)));

__device__ inline unsigned short f2bf(float f) {
  union { float f; unsigned u; } v; v.f = f;
  return (unsigned short)((v.u + 0x7fffu + ((v.u >> 16) & 1u)) >> 16);  // RNE
}

__device__ inline void gld_lds16(const void* gptr, void* lptr) {
  __builtin_amdgcn_global_load_lds(
      (const __attribute__((address_space(1))) void*)(uintptr_t)gptr,
      (__attribute__((address_space(3))) void*)(uintptr_t)lptr,
      16, 0, 0);
}

// ---------------- f32 -> bf16 conversion (weights) ----------------
__global__ __launch_bounds__(256) void cvt_kernel(const float* __restrict__ src,
                                                  unsigned short* __restrict__ dst,
                                                  int n4) {
  int i = blockIdx.x * 256 + threadIdx.x;
  int stride = gridDim.x * 256;
  for (; i < n4; i += stride) {
    float4 v = reinterpret_cast<const float4*>(src)[i];
    ushort4 o;
    o.x = f2bf(v.x); o.y = f2bf(v.y); o.z = f2bf(v.z); o.w = f2bf(v.w);
    reinterpret_cast<ushort4*>(dst)[i] = o;
  }
}

// ---------------- router: logits, top-2, softmax -> pair/probs (NO atomics) ----------------
__global__ __launch_bounds__(256) void router_kernel(
    const float* __restrict__ tokens, const float* __restrict__ rw,
    unsigned short* __restrict__ tokb, int* __restrict__ pair,
    float* __restrict__ probs) {
  int wid = threadIdx.x >> 6, lane = threadIdx.x & 63;
  int n = blockIdx.x * 4 + wid;
  const float4* trow = (const float4*)(tokens + (size_t)n * HDIM);
  ushort4* tdst = (ushort4*)(tokb + (size_t)n * HDIM);
  float acc[NEXP];
#pragma unroll
  for (int e = 0; e < NEXP; e++) acc[e] = 0.f;
#pragma unroll
  for (int it = 0; it < 4; it++) {
    int c4 = it * 64 + lane;
    float4 tv = trow[c4];
    ushort4 o;
    o.x = f2bf(tv.x); o.y = f2bf(tv.y); o.z = f2bf(tv.z); o.w = f2bf(tv.w);
    tdst[c4] = o;
#pragma unroll
    for (int e = 0; e < NEXP; e++) {
      float4 w = ((const float4*)(rw + e * HDIM))[c4];
      acc[e] += tv.x * w.x + tv.y * w.y + tv.z * w.z + tv.w * w.w;
    }
  }
#pragma unroll
  for (int e = 0; e < NEXP; e++) {
#pragma unroll
    for (int off = 32; off > 0; off >>= 1) acc[e] += __shfl_xor(acc[e], off, 64);
  }
  if (lane == 0) {
    int e0 = 0; float s0 = acc[0];
#pragma unroll
    for (int e = 1; e < NEXP; e++) if (acc[e] > s0) { s0 = acc[e]; e0 = e; }
    int e1 = -1; float s1 = -3.4e38f;
#pragma unroll
    for (int e = 0; e < NEXP; e++) if (e != e0 && acc[e] > s1) { s1 = acc[e]; e1 = e; }
    float z  = expf(s1 - s0);
    float p0 = 1.f / (1.f + z);
    pair[n] = e0 | (e1 << 8);
    probs[2 * n]     = p0;
    probs[2 * n + 1] = z * p0;
  }
}

// ---------------- dispatch: deterministic per-expert compaction via LDS scan ----------------
__global__ __launch_bounds__(1024) void dispatch_kernel(
    const int* __restrict__ pair, int* __restrict__ counts,
    int* __restrict__ rowids) {
  int e = blockIdx.x;
  int t = threadIdx.x;
  __shared__ int sc[1024];
  int p8[8];
  int c = 0;
#pragma unroll
  for (int i = 0; i < 8; i++) {
    p8[i] = pair[t * 8 + i];
    c += ((p8[i] & 255) == e) + (((p8[i] >> 8) & 255) == e);
  }
  sc[t] = c;
  __syncthreads();
  for (int off = 1; off < 1024; off <<= 1) {
    int v = (t >= off) ? sc[t - off] : 0;
    __syncthreads();
    sc[t] += v;
    __syncthreads();
  }
  if (t == 1023) counts[e] = sc[1023];
  int* dst = rowids + e * CAP + (sc[t] - c);
#pragma unroll
  for (int i = 0; i < 8; i++) {
    int n = t * 8 + i;
    if ((p8[i] & 255) == e)        *dst++ = 2 * n;
    if (((p8[i] >> 8) & 255) == e) *dst++ = 2 * n + 1;
  }
}

// ---------------- gathered NT bf16 GEMM, 2-phase prefetch double-buffer ----------------
// MODE 0 = fc1(+gelu->Hbuf), MODE 1 = fc2(+prob*atomicAdd->out)
template <int MODE>
__global__ __launch_bounds__(256) void moe_gemm(
    const unsigned short* __restrict__ Abase,
    const unsigned short* __restrict__ Wb,
    const float* __restrict__ bias,
    const int* __restrict__ counts, const int* __restrict__ rowids,
    const float* __restrict__ probs,
    unsigned short* __restrict__ Hbuf, float* __restrict__ out) {
  constexpr int CB   = MODE ? 8 : 16;      // 128-col blocks over N
  constexpr int KT   = MODE ? 32 : 16;     // K / 64
  constexpr int NCOL = MODE ? 1024 : 2048;
  constexpr int KDIM = MODE ? 2048 : 1024;

  int bid = blockIdx.x;
  int cb = bid % CB;
  int rb = (bid / CB) & 63;
  int e  = bid / (CB * 64);
  int ce = counts[e];
  if (rb * 128 >= ce) return;
  const int* rl = rowids + e * CAP + rb * 128;

  int t = threadIdx.x;
  __shared__ __align__(16) char smem[2][32768];  // per buf: A[128][64]bf16 @0, B @16384

  // staging chunk c covers 16B at LDS byte c*16; row=c>>3, phys col-chunk=c&7
  // src col-chunk = (c&7) ^ (row&7)  (XOR involution) so swizzled ds_read sees linear data
  int jsrc = (t & 7) ^ ((t >> 3) & 7);
  const char* asrc[4];
  const char* bsrc[4];
#pragma unroll
  for (int i = 0; i < 4; i++) {
    int r = i * 32 + (t >> 3);
    int rid = (rb * 128 + r < ce) ? rl[r] : rl[0];  // clamp tail to a valid row
    long arow = MODE ? (long)rid : (long)(rid >> 1);
    asrc[i] = (const char*)(Abase + arow * KDIM) + jsrc * 16;
    bsrc[i] = (const char*)(Wb + ((long)e * NCOL + cb * 128 + r) * KDIM) + jsrc * 16;
  }

  f32x4 acc[4][4];
#pragma unroll
  for (int mi = 0; mi < 4; mi++)
#pragma unroll
    for (int ni = 0; ni < 4; ni++) {
      f32x4 z = {0.f, 0.f, 0.f, 0.f};
      acc[mi][ni] = z;
    }

  int lane = t & 63, wid = t >> 6;
  int wr = wid >> 1, wc = wid & 1;        // 2x2 wave grid, 64x64 per wave
  int lr = lane >> 4, lc = lane & 15;

  auto stage = [&](int buf, int kt) {
#pragma unroll
    for (int i = 0; i < 4; i++) {
      gld_lds16(asrc[i] + kt * 128, smem[buf] + t * 16 + i * 4096);
      gld_lds16(bsrc[i] + kt * 128, smem[buf] + 16384 + t * 16 + i * 4096);
    }
  };

  stage(0, 0);
  __syncthreads();          // drains vmcnt(0): buf0 ready
  int cur = 0;
  for (int kt = 0; kt < KT; kt++) {
    if (kt + 1 < KT) stage(cur ^ 1, kt + 1);   // prefetch next tile (in flight across MFMA)
#pragma unroll
    for (int ks = 0; ks < 2; ks++) {
      bf16x8 af[4], bfr[4];
#pragma unroll
      for (int mi = 0; mi < 4; mi++) {
        int r = wr * 64 + mi * 16 + lc;
        int j = ks * 4 + lr;
        af[mi] = *(const bf16x8*)(smem[cur] + r * 128 + ((j ^ (r & 7)) * 16));
      }
#pragma unroll
      for (int ni = 0; ni < 4; ni++) {
        int r = wc * 64 + ni * 16 + lc;
        int j = ks * 4 + lr;
        bfr[ni] = *(const bf16x8*)(smem[cur] + 16384 + r * 128 + ((j ^ (r & 7)) * 16));
      }
#pragma unroll
      for (int mi = 0; mi < 4; mi++)
#pragma unroll
        for (int ni = 0; ni < 4; ni++)
          acc[mi][ni] = __builtin_amdgcn_mfma_f32_16x16x32_bf16(af[mi], bfr[ni], acc[mi][ni], 0, 0, 0);
    }
    __syncthreads();        // one barrier/K-step: drains stage writes + read completion
    cur ^= 1;
  }

  // epilogue: C/D layout col=lane&15, row=(lane>>4)*4+reg
#pragma unroll
  for (int mi = 0; mi < 4; mi++) {
#pragma unroll
    for (int r4 = 0; r4 < 4; r4++) {
      int lrow = wr * 64 + mi * 16 + lr * 4 + r4;
      if (rb * 128 + lrow < ce) {
        int rid = rl[lrow];
#pragma unroll
        for (int ni = 0; ni < 4; ni++) {
          int col = cb * 128 + wc * 64 + ni * 16 + lc;
          float x = acc[mi][ni][r4] + bias[e * NCOL + col];
          if constexpr (MODE == 0) {
            x = 0.5f * x * (1.f + erff(x * 0.70710678118654752f));  // exact gelu
            Hbuf[(long)rid * 2048 + col] = f2bf(x);
          } else {
            atomicAdd(out + (long)(rid >> 1) * HDIM + col, x * probs[rid]);
          }
        }
      }
    }
  }
}

extern "C" void kernel_launch(void* const* d_in, const int* in_sizes, int n_in,
                              void* d_out, int out_size, void* d_ws, size_t ws_size,
                              hipStream_t stream) {
  const float* tokens   = (const float*)d_in[0];
  const float* router_w = (const float*)d_in[1];
  const float* w1       = (const float*)d_in[2];
  const float* b1       = (const float*)d_in[3];
  const float* w2       = (const float*)d_in[4];
  const float* b2       = (const float*)d_in[5];
  float* out = (float*)d_out;

  // ws layout (bytes):
  //   0        counts[8]
  //   64       rowids[8][16384] int          (512 KiB)
  //   +512K    probs[16384] f32              (64 KiB)
  //   +64K     pair[8192] int                (32 KiB)
  //   1 MiB    tokens_bf16 [8192][1024]      (16 MiB)
  //   +16M     w1b [8][2048][1024] bf16      (32 MiB)
  //   +48M     w2b [8][1024][2048] bf16      (32 MiB)
  //   +80M     Hbuf [16384][2048] bf16       (64 MiB)   total ~145 MiB
  char* ws = (char*)d_ws;
  int*            counts = (int*)ws;
  int*            rowids = (int*)(ws + 64);
  float*          probs  = (float*)(ws + 64 + NEXP * CAP * 4);
  int*            pair   = (int*)(ws + 64 + NEXP * CAP * 4 + N_TOK * 2 * 4);
  unsigned short* tokb   = (unsigned short*)(ws + (1u << 20));
  unsigned short* w1b    = (unsigned short*)(ws + (1u << 20) + 16777216u);
  unsigned short* w2b    = (unsigned short*)(ws + (1u << 20) + 16777216u + 33554432u);
  unsigned short* Hbuf   = (unsigned short*)(ws + (1u << 20) + 16777216u + 67108864u);

  hipMemsetAsync(d_out, 0, (size_t)out_size * sizeof(float), stream);

  cvt_kernel<<<2048, 256, 0, stream>>>(w1, w1b, NEXP * 2048 * 1024 / 4);
  cvt_kernel<<<2048, 256, 0, stream>>>(w2, w2b, NEXP * 1024 * 2048 / 4);
  router_kernel<<<N_TOK / 4, 256, 0, stream>>>(tokens, router_w, tokb, pair, probs);
  dispatch_kernel<<<NEXP, 1024, 0, stream>>>(pair, counts, rowids);
  moe_gemm<0><<<NEXP * 64 * 16, 256, 0, stream>>>(tokb, w1b, b1, counts, rowids, probs, Hbuf, out);
  moe_gemm<1><<<NEXP * 64 * 8, 256, 0, stream>>>(Hbuf, w2b, b2, counts, rowids, probs, Hbuf, out);
}

// Round 3
// 411.054 us; speedup vs baseline: 1.4372x; 1.0347x over previous
//
#include <hip/hip_runtime.h>
#include <stdint.h>

#define N_TOK 8192
#define HDIM  1024
#define NEXP  8
#define CAP   16384   // per-expert rowid list capacity

typedef __bf16 bf16x8 __attribute__((ext_vector_type(8)));
typedef float  f32x4  __attribute__((ext_vector_type(4)));

__device__ inline unsigned short f2bf(float f) {
  union { float f; unsigned u; } v; v.f = f;
  return (unsigned short)((v.u + 0x7fffu + ((v.u >> 16) & 1u)) >> 16);  // RNE
}

__device__ inline void gld_lds16(const void* gptr, void* lptr) {
  __builtin_amdgcn_global_load_lds(
      (const __attribute__((address_space(1))) void*)(uintptr_t)gptr,
      (__attribute__((address_space(3))) void*)(uintptr_t)lptr,
      16, 0, 0);
}

// ---------------- f32 -> bf16 conversion (weights) ----------------
__global__ __launch_bounds__(256) void cvt_kernel(const float* __restrict__ src,
                                                  unsigned short* __restrict__ dst,
                                                  int n4) {
  int i = blockIdx.x * 256 + threadIdx.x;
  int stride = gridDim.x * 256;
  for (; i < n4; i += stride) {
    float4 v = reinterpret_cast<const float4*>(src)[i];
    ushort4 o;
    o.x = f2bf(v.x); o.y = f2bf(v.y); o.z = f2bf(v.z); o.w = f2bf(v.w);
    reinterpret_cast<ushort4*>(dst)[i] = o;
  }
}

// ---------------- router: logits, top-2, softmax -> pair/probs (NO atomics) ----------------
__global__ __launch_bounds__(256) void router_kernel(
    const float* __restrict__ tokens, const float* __restrict__ rw,
    unsigned short* __restrict__ tokb, int* __restrict__ pair,
    float* __restrict__ probs) {
  int wid = threadIdx.x >> 6, lane = threadIdx.x & 63;
  int n = blockIdx.x * 4 + wid;
  const float4* trow = (const float4*)(tokens + (size_t)n * HDIM);
  ushort4* tdst = (ushort4*)(tokb + (size_t)n * HDIM);
  float acc[NEXP];
#pragma unroll
  for (int e = 0; e < NEXP; e++) acc[e] = 0.f;
#pragma unroll
  for (int it = 0; it < 4; it++) {
    int c4 = it * 64 + lane;
    float4 tv = trow[c4];
    ushort4 o;
    o.x = f2bf(tv.x); o.y = f2bf(tv.y); o.z = f2bf(tv.z); o.w = f2bf(tv.w);
    tdst[c4] = o;
#pragma unroll
    for (int e = 0; e < NEXP; e++) {
      float4 w = ((const float4*)(rw + e * HDIM))[c4];
      acc[e] += tv.x * w.x + tv.y * w.y + tv.z * w.z + tv.w * w.w;
    }
  }
#pragma unroll
  for (int e = 0; e < NEXP; e++) {
#pragma unroll
    for (int off = 32; off > 0; off >>= 1) acc[e] += __shfl_xor(acc[e], off, 64);
  }
  if (lane == 0) {
    int e0 = 0; float s0 = acc[0];
#pragma unroll
    for (int e = 1; e < NEXP; e++) if (acc[e] > s0) { s0 = acc[e]; e0 = e; }
    int e1 = -1; float s1 = -3.4e38f;
#pragma unroll
    for (int e = 0; e < NEXP; e++) if (e != e0 && acc[e] > s1) { s1 = acc[e]; e1 = e; }
    float z  = expf(s1 - s0);
    float p0 = 1.f / (1.f + z);
    pair[n] = e0 | (e1 << 8);
    probs[2 * n]     = p0;
    probs[2 * n + 1] = z * p0;
  }
}

// ---------------- dispatch: deterministic per-expert compaction via LDS scan ----------------
__global__ __launch_bounds__(1024) void dispatch_kernel(
    const int* __restrict__ pair, int* __restrict__ counts,
    int* __restrict__ rowids) {
  int e = blockIdx.x;
  int t = threadIdx.x;
  __shared__ int sc[1024];
  int p8[8];
  int c = 0;
#pragma unroll
  for (int i = 0; i < 8; i++) {
    p8[i] = pair[t * 8 + i];
    c += ((p8[i] & 255) == e) + (((p8[i] >> 8) & 255) == e);
  }
  sc[t] = c;
  __syncthreads();
  for (int off = 1; off < 1024; off <<= 1) {
    int v = (t >= off) ? sc[t - off] : 0;
    __syncthreads();
    sc[t] += v;
    __syncthreads();
  }
  if (t == 1023) counts[e] = sc[1023];
  int* dst = rowids + e * CAP + (sc[t] - c);
#pragma unroll
  for (int i = 0; i < 8; i++) {
    int n = t * 8 + i;
    if ((p8[i] & 255) == e)        *dst++ = 2 * n;
    if (((p8[i] >> 8) & 255) == e) *dst++ = 2 * n + 1;
  }
}

// ---------------- gathered NT bf16 GEMM, 2-phase prefetch dbuf, expert->XCD pinned ---------
// MODE 0 = fc1(+gelu->Hbuf), MODE 1 = fc2(+prob*atomicAdd->out)
// blockIdx.x & 7 == expert: round-robin block->XCD dispatch pins expert e to XCD e,
// whose 4 MiB L2 exactly holds that expert's weight matrix.
template <int MODE>
__global__ __launch_bounds__(256) void moe_gemm(
    const unsigned short* __restrict__ Abase,
    const unsigned short* __restrict__ Wb,
    const float* __restrict__ bias,
    const int* __restrict__ counts, const int* __restrict__ rowids,
    const float* __restrict__ probs,
    unsigned short* __restrict__ Hbuf, float* __restrict__ out) {
  constexpr int CB   = MODE ? 8 : 16;      // 128-col blocks over N
  constexpr int KT   = MODE ? 32 : 16;     // K / 64
  constexpr int NCOL = MODE ? 1024 : 2048;
  constexpr int KDIM = MODE ? 2048 : 1024;

  int bid = blockIdx.x;
  int e     = bid & 7;          // expert -> XCD pin
  int inner = bid >> 3;         // cb fastest: consecutive same-XCD blocks share A-panel
  int cb = inner % CB;
  int rb = inner / CB;
  int ce = counts[e];
  if (rb * 128 >= ce) return;
  const int* rl = rowids + e * CAP + rb * 128;

  int t = threadIdx.x;
  __shared__ __align__(16) char smem[2][32768];  // per buf: A[128][64]bf16 @0, B @16384

  // staging chunk c covers 16B at LDS byte c*16; row=c>>3, phys col-chunk=c&7
  // src col-chunk = (c&7) ^ (row&7)  (XOR involution) so swizzled ds_read sees linear data
  int jsrc = (t & 7) ^ ((t >> 3) & 7);
  const char* asrc[4];
  const char* bsrc[4];
#pragma unroll
  for (int i = 0; i < 4; i++) {
    int r = i * 32 + (t >> 3);
    int rid = (rb * 128 + r < ce) ? rl[r] : rl[0];  // clamp tail to a valid row
    long arow = MODE ? (long)rid : (long)(rid >> 1);
    asrc[i] = (const char*)(Abase + arow * KDIM) + jsrc * 16;
    bsrc[i] = (const char*)(Wb + ((long)e * NCOL + cb * 128 + r) * KDIM) + jsrc * 16;
  }

  f32x4 acc[4][4];
#pragma unroll
  for (int mi = 0; mi < 4; mi++)
#pragma unroll
    for (int ni = 0; ni < 4; ni++) {
      f32x4 z = {0.f, 0.f, 0.f, 0.f};
      acc[mi][ni] = z;
    }

  int lane = t & 63, wid = t >> 6;
  int wr = wid >> 1, wc = wid & 1;        // 2x2 wave grid, 64x64 per wave
  int lr = lane >> 4, lc = lane & 15;

  auto stage = [&](int buf, int kt) {
#pragma unroll
    for (int i = 0; i < 4; i++) {
      gld_lds16(asrc[i] + kt * 128, smem[buf] + t * 16 + i * 4096);
      gld_lds16(bsrc[i] + kt * 128, smem[buf] + 16384 + t * 16 + i * 4096);
    }
  };

  stage(0, 0);
  __syncthreads();          // drains vmcnt(0): buf0 ready
  int cur = 0;
  for (int kt = 0; kt < KT; kt++) {
    if (kt + 1 < KT) stage(cur ^ 1, kt + 1);   // prefetch next tile
#pragma unroll
    for (int ks = 0; ks < 2; ks++) {
      bf16x8 af[4], bfr[4];
#pragma unroll
      for (int mi = 0; mi < 4; mi++) {
        int r = wr * 64 + mi * 16 + lc;
        int j = ks * 4 + lr;
        af[mi] = *(const bf16x8*)(smem[cur] + r * 128 + ((j ^ (r & 7)) * 16));
      }
#pragma unroll
      for (int ni = 0; ni < 4; ni++) {
        int r = wc * 64 + ni * 16 + lc;
        int j = ks * 4 + lr;
        bfr[ni] = *(const bf16x8*)(smem[cur] + 16384 + r * 128 + ((j ^ (r & 7)) * 16));
      }
#pragma unroll
      for (int mi = 0; mi < 4; mi++)
#pragma unroll
        for (int ni = 0; ni < 4; ni++)
          acc[mi][ni] = __builtin_amdgcn_mfma_f32_16x16x32_bf16(af[mi], bfr[ni], acc[mi][ni], 0, 0, 0);
    }
    __syncthreads();
    cur ^= 1;
  }

  // epilogue: C/D layout col=lane&15, row=(lane>>4)*4+reg
#pragma unroll
  for (int mi = 0; mi < 4; mi++) {
#pragma unroll
    for (int r4 = 0; r4 < 4; r4++) {
      int lrow = wr * 64 + mi * 16 + lr * 4 + r4;
      if (rb * 128 + lrow < ce) {
        int rid = rl[lrow];
#pragma unroll
        for (int ni = 0; ni < 4; ni++) {
          int col = cb * 128 + wc * 64 + ni * 16 + lc;
          float x = acc[mi][ni][r4] + bias[e * NCOL + col];
          if constexpr (MODE == 0) {
            x = 0.5f * x * (1.f + erff(x * 0.70710678118654752f));  // exact gelu
            Hbuf[(long)rid * 2048 + col] = f2bf(x);
          } else {
            atomicAdd(out + (long)(rid >> 1) * HDIM + col, x * probs[rid]);
          }
        }
      }
    }
  }
}

extern "C" void kernel_launch(void* const* d_in, const int* in_sizes, int n_in,
                              void* d_out, int out_size, void* d_ws, size_t ws_size,
                              hipStream_t stream) {
  const float* tokens   = (const float*)d_in[0];
  const float* router_w = (const float*)d_in[1];
  const float* w1       = (const float*)d_in[2];
  const float* b1       = (const float*)d_in[3];
  const float* w2       = (const float*)d_in[4];
  const float* b2       = (const float*)d_in[5];
  float* out = (float*)d_out;

  // ws layout (bytes):
  //   0        counts[8]
  //   64       rowids[8][16384] int          (512 KiB)
  //   +512K    probs[16384] f32              (64 KiB)
  //   +64K     pair[8192] int                (32 KiB)
  //   1 MiB    tokens_bf16 [8192][1024]      (16 MiB)
  //   +16M     w1b [8][2048][1024] bf16      (32 MiB)
  //   +48M     w2b [8][1024][2048] bf16      (32 MiB)
  //   +80M     Hbuf [16384][2048] bf16       (64 MiB)   total ~145 MiB
  char* ws = (char*)d_ws;
  int*            counts = (int*)ws;
  int*            rowids = (int*)(ws + 64);
  float*          probs  = (float*)(ws + 64 + NEXP * CAP * 4);
  int*            pair   = (int*)(ws + 64 + NEXP * CAP * 4 + N_TOK * 2 * 4);
  unsigned short* tokb   = (unsigned short*)(ws + (1u << 20));
  unsigned short* w1b    = (unsigned short*)(ws + (1u << 20) + 16777216u);
  unsigned short* w2b    = (unsigned short*)(ws + (1u << 20) + 16777216u + 33554432u);
  unsigned short* Hbuf   = (unsigned short*)(ws + (1u << 20) + 16777216u + 67108864u);

  hipMemsetAsync(d_out, 0, (size_t)out_size * sizeof(float), stream);

  cvt_kernel<<<2048, 256, 0, stream>>>(w1, w1b, NEXP * 2048 * 1024 / 4);
  cvt_kernel<<<2048, 256, 0, stream>>>(w2, w2b, NEXP * 1024 * 2048 / 4);
  router_kernel<<<N_TOK / 4, 256, 0, stream>>>(tokens, router_w, tokb, pair, probs);
  dispatch_kernel<<<NEXP, 1024, 0, stream>>>(pair, counts, rowids);
  moe_gemm<0><<<NEXP * 64 * 16, 256, 0, stream>>>(tokb, w1b, b1, counts, rowids, probs, Hbuf, out);
  moe_gemm<1><<<NEXP * 64 * 8, 256, 0, stream>>>(Hbuf, w2b, b2, counts, rowids, probs, Hbuf, out);
}